// Round 1
// 280.003 us; speedup vs baseline: 1.0263x; 1.0263x over previous
//
#include <hip/hip_runtime.h>
#include <math.h>

#define N_NODES 20000
#define N_EDGES 320000
#define EMB 128
#define HID 512          // 4*EMB
#define ROWS_PER_BLOCK 16
#define SC_CAP 2048      // LDS score cache per block
#define NCHUNK ((N_NODES + 1023) / 1024)   // 20

typedef float v2f __attribute__((ext_vector_type(2)));

#if defined(__has_builtin)
#if __has_builtin(__builtin_elementwise_fma)
#define V2FMA(a, b, c) __builtin_elementwise_fma((a), (b), (c))
#else
#define V2FMA(a, b, c) ((a) * (b) + (c))
#endif
#else
#define V2FMA(a, b, c) ((a) * (b) + (c))
#endif

// ---------------------------------------------------------------------------
__global__ void init_deg(int* __restrict__ deg, int* __restrict__ offs) {
    int i = blockIdx.x * 256 + threadIdx.x;
    if (i < N_NODES) deg[i] = 0;
    if (i == 0) offs[N_NODES] = N_EDGES;
}

// ---------------------------------------------------------------------------
// K2: heterogeneous blocks — [0,GEMM_BLOCKS) = GEMM, rest = row histogram.
// GEMM: P[n][0:512] = h@W1[0:128,:] + b1 ; Q[n][0:512] = h@W1[128:256,:]
// 128x128 tile, BK=8, 256 thr, 8x8 micro (pk-fma), LDS double-buffer.
// ---------------------------------------------------------------------------
#define TM 128
#define TN 128
#define BK 8
#define NTILES (EMB / BK)                   // 16
#define GEMM_MT ((N_NODES + TM - 1) / TM)   // 157
#define GEMM_BLOCKS (8 * GEMM_MT)           // 1256
#define HIST_BLOCKS ((N_EDGES + 255) / 256) // 1250

__global__ __launch_bounds__(256) void gemm_hist(
    const float* __restrict__ h, const float* __restrict__ W1,
    const float* __restrict__ b1, float* __restrict__ P, float* __restrict__ Q,
    const int* __restrict__ row, int* __restrict__ deg)
{
    const int bid = blockIdx.x;
    const int tid = threadIdx.x;

    if (bid >= GEMM_BLOCKS) {
        // ---- histogram path ----
        const int e = (bid - GEMM_BLOCKS) * 256 + tid;
        if (e < N_EDGES) atomicAdd(&deg[row[e]], 1);
        return;
    }

    // ---- gemm path ----
    __shared__ float As[2][BK][TM + 4];
    __shared__ float Bs[2][BK][TN];

    const int nt = bid & 7;        // 0..7 (1256 = 8*157 exactly)
    const int mt = bid >> 3;       // 0..156
    const int m_base = mt * TM;

    const int a_m = tid >> 1;
    const int a_k = (tid & 1) << 2;
    const int  row_a = m_base + a_m;
    const bool a_ok  = row_a < N_NODES;
    const float* __restrict__ hrow = h + (size_t)row_a * EMB + a_k;

    const int b_k = tid >> 5;
    const int b_n = (tid & 31) << 2;
    const int w_row_off = (nt < 4) ? 0 : 128;
    const int w_col     = (nt & 3) * TN + b_n;
    const float* __restrict__ wrow = W1 + (size_t)(w_row_off + b_k) * HID + w_col;

    const int ty = tid >> 4, tx = tid & 15;
    const int cm = ty << 2, cn = tx << 2;

    v2f acc[8][4] = {};

    float4 pa, pb;
    pa = make_float4(0.f, 0.f, 0.f, 0.f);
    if (a_ok) pa = *(const float4*)(hrow);
    pb = *(const float4*)(wrow);
    As[0][a_k + 0][a_m] = pa.x;
    As[0][a_k + 1][a_m] = pa.y;
    As[0][a_k + 2][a_m] = pa.z;
    As[0][a_k + 3][a_m] = pa.w;
    *(float4*)&Bs[0][b_k][b_n] = pb;
    __syncthreads();

    for (int t = 0; t < NTILES; ++t) {
        const int cur = t & 1;
        if (t + 1 < NTILES) {
            const int k0 = (t + 1) * BK;
            pa = make_float4(0.f, 0.f, 0.f, 0.f);
            if (a_ok) pa = *(const float4*)(hrow + k0);
            pb = *(const float4*)(wrow + (size_t)k0 * HID);
        }

#pragma unroll
        for (int kk = 0; kk < BK; ++kk) {
            float a[8];
            *(float4*)&a[0] = *(const float4*)&As[cur][kk][cm];
            *(float4*)&a[4] = *(const float4*)&As[cur][kk][cm + 64];
            float4 b0 = *(const float4*)&Bs[cur][kk][cn];
            float4 b1v = *(const float4*)&Bs[cur][kk][cn + 64];
            v2f bp[4] = {(v2f){b0.x, b0.y}, (v2f){b0.z, b0.w},
                         (v2f){b1v.x, b1v.y}, (v2f){b1v.z, b1v.w}};
#pragma unroll
            for (int i = 0; i < 8; ++i) {
                v2f ai = (v2f){a[i], a[i]};
#pragma unroll
                for (int j = 0; j < 4; ++j)
                    acc[i][j] = V2FMA(ai, bp[j], acc[i][j]);
            }
        }

        if (t + 1 < NTILES) {
            const int nxt = 1 - cur;
            As[nxt][a_k + 0][a_m] = pa.x;
            As[nxt][a_k + 1][a_m] = pa.y;
            As[nxt][a_k + 2][a_m] = pa.z;
            As[nxt][a_k + 3][a_m] = pa.w;
            *(float4*)&Bs[nxt][b_k][b_n] = pb;
            __syncthreads();
        }
    }

    const bool  isP = (nt < 4);
    const int   col_base = (nt & 3) * TN;
    float* __restrict__ dstbase = isP ? P : Q;

    v2f bias[4] = {{0.f,0.f},{0.f,0.f},{0.f,0.f},{0.f,0.f}};
    if (isP) {  // bias fold: P half only
        float4 bv0 = *(const float4*)(b1 + col_base + cn);
        float4 bv1 = *(const float4*)(b1 + col_base + cn + 64);
        bias[0] = (v2f){bv0.x, bv0.y};
        bias[1] = (v2f){bv0.z, bv0.w};
        bias[2] = (v2f){bv1.x, bv1.y};
        bias[3] = (v2f){bv1.z, bv1.w};
    }

#pragma unroll
    for (int i = 0; i < 8; ++i) {
        const int r = m_base + cm + (i < 4 ? i : 64 + i - 4);
        if (r < N_NODES) {
            float* dst = dstbase + (size_t)r * HID + col_base;
            v2f c0 = acc[i][0] + bias[0], c1 = acc[i][1] + bias[1];
            v2f c2 = acc[i][2] + bias[2], c3 = acc[i][3] + bias[3];
            *(float4*)(dst + cn)      = make_float4(c0.x, c0.y, c1.x, c1.y);
            *(float4*)(dst + cn + 64) = make_float4(c2.x, c2.y, c3.x, c3.y);
        }
    }
}

// ---------------------------------------------------------------------------
__device__ __forceinline__ int wave_incl_scan(int v, int lane) {
#pragma unroll
    for (int off = 1; off < 64; off <<= 1) {
        int t = __shfl_up(v, off, 64);
        if (lane >= off) v += t;
    }
    return v;
}

__global__ __launch_bounds__(1024) void scan_part(const int* __restrict__ deg,
                                                  int* __restrict__ part,
                                                  int* __restrict__ totals) {
    __shared__ int wsum[16];
    const int tid = threadIdx.x, lane = tid & 63, w = tid >> 6;
    const int i = blockIdx.x * 1024 + tid;
    int v = (i < N_NODES) ? deg[i] : 0;
    int incl = wave_incl_scan(v, lane);
    if (lane == 63) wsum[w] = incl;
    __syncthreads();
    if (w == 0) {
        int x = (lane < 16) ? wsum[lane] : 0;
        int xs = wave_incl_scan(x, lane);
        if (lane < 16) wsum[lane] = xs - x;
        if (lane == 15) totals[blockIdx.x] = xs;
    }
    __syncthreads();
    if (i < N_NODES) part[i] = wsum[w] + incl - v;
}

__global__ __launch_bounds__(1024) void scan_apply(const int* __restrict__ part,
                                                   const int* __restrict__ totals,
                                                   int* __restrict__ cursor,
                                                   int* __restrict__ offs) {
    __shared__ int carry_s;
    const int tid = threadIdx.x;
    if (tid < 64) {
        int v = (tid < NCHUNK) ? totals[tid] : 0;
        int incl = wave_incl_scan(v, tid);
        if (tid == (int)blockIdx.x) carry_s = incl - v;   // exclusive carry
    }
    __syncthreads();
    const int i = blockIdx.x * 1024 + tid;
    if (i < N_NODES) {
        int o = part[i] + carry_s;
        cursor[i] = o;
        offs[i] = o;
    }
}

// ---------------------------------------------------------------------------
// scatter: cols16[pos] = col (u16, lossless: col < 20000) in CSR order, and
// inv[e] = pos (sequential write) so the final unperm kernel can run in
// ORIGINAL edge order with fully coalesced output writes.
// ---------------------------------------------------------------------------
__global__ void scatter_edges(const int* __restrict__ row, const int* __restrict__ col,
                              int* __restrict__ cursor,
                              unsigned short* __restrict__ cols16,
                              int* __restrict__ inv) {
    int e = blockIdx.x * 256 + threadIdx.x;
    if (e >= N_EDGES) return;
    int r = row[e];
    int pos = atomicAdd(&cursor[r], 1);
    cols16[pos] = (unsigned short)col[e];
    inv[e] = pos;
}

// ---------------------------------------------------------------------------
// Fused edge phase, round-9 restructure:
//  * row-centric: one wave per CSR row; P row loaded ONCE into regs (halves
//    gather instruction count vs per-edge P reload)
//  * 4 edges per batch with a depth-1 software pipeline (issue next batch's
//    8 Q float4 loads before computing current batch) -> ~2x latency hiding
//  * per-row softmax fused right after the row's scores -> NO __syncthreads
//    anywhere (waves fully independent; imbalance no longer stalls the block)
//  * output: only a sorted-order float2 {score, logits} tmp array (coalesced,
//    2.56 MB = L2-resident). All random 4B scatters / random u+mask reads
//    moved to the sequential unperm kernel -> kills the 57 MB write
//    amplification + its RFO fetches.
// Score arithmetic (fmaf chain order, shfl_down tree, +bias2 at lane 0) is
// bit-identical to the previous champion.
// ---------------------------------------------------------------------------
__global__ __launch_bounds__(256) void fused_edge(
    const float* __restrict__ P, const float* __restrict__ Q,
    const float* __restrict__ W2, const float* __restrict__ b2,
    const unsigned short* __restrict__ cols16, const int* __restrict__ offs,
    float2* __restrict__ tmp)
{
    __shared__ float sc_lds[SC_CAP];

    const int r0 = blockIdx.x * ROWS_PER_BLOCK;
    const int r1 = (r0 + ROWS_PER_BLOCK < N_NODES) ? r0 + ROWS_PER_BLOCK : N_NODES;
    const int e0 = offs[r0];
    const int tid = threadIdx.x, lane = tid & 63, w = tid >> 6;
    const int j0 = lane << 2;

    const float4 w0 = *(const float4*)(W2 + j0);
    const float4 w1 = *(const float4*)(W2 + 256 + j0);
    const float bias2 = b2[0];

    for (int r = r0 + w; r < r1; r += 4) {
        const int es = offs[r], ee = offs[r + 1];
        const int d = ee - es;
        if (d == 0) continue;

        // P row resident in regs for the whole row
        const float* __restrict__ prow = P + (size_t)r * HID;
        const float4 p0 = *(const float4*)(prow + j0);
        const float4 p1 = *(const float4*)(prow + 256 + j0);

        for (int base = 0; base < d; base += 64) {
            const int nch = (d - base < 64) ? d - base : 64;
            int mycol = 0;                         // masked lanes -> Q row 0 (safe, discarded)
            if (lane < nch) mycol = (int)cols16[es + base + lane];

#define QL(k, bb, d0, d1) { \
                int c_ = __shfl(mycol, (bb) + (k), 64); \
                const float* __restrict__ q_ = Q + (size_t)c_ * HID; \
                d0 = *(const float4*)(q_ + j0); \
                d1 = *(const float4*)(q_ + 256 + j0); }

            float4 q00,q01,q10,q11,q20,q21,q30,q31;
            QL(0,0,q00,q01); QL(1,0,q10,q11); QL(2,0,q20,q21); QL(3,0,q30,q31);

            for (int b = 0; b < nch; b += 4) {
                float4 n00,n01,n10,n11,n20,n21,n30,n31;
                const bool more = (b + 4) < nch;
                if (more) {
                    QL(0,b+4,n00,n01); QL(1,b+4,n10,n11);
                    QL(2,b+4,n20,n21); QL(3,b+4,n30,n31);
                }

                float s0, s1, s2, s3;
#define DOT8(qa, qb, sd) { \
                    float t_ = 0.0f; \
                    t_ = fmaf(fmaxf(p0.x + qa.x, 0.0f), w0.x, t_); \
                    t_ = fmaf(fmaxf(p0.y + qa.y, 0.0f), w0.y, t_); \
                    t_ = fmaf(fmaxf(p0.z + qa.z, 0.0f), w0.z, t_); \
                    t_ = fmaf(fmaxf(p0.w + qa.w, 0.0f), w0.w, t_); \
                    t_ = fmaf(fmaxf(p1.x + qb.x, 0.0f), w1.x, t_); \
                    t_ = fmaf(fmaxf(p1.y + qb.y, 0.0f), w1.y, t_); \
                    t_ = fmaf(fmaxf(p1.z + qb.z, 0.0f), w1.z, t_); \
                    t_ = fmaf(fmaxf(p1.w + qb.w, 0.0f), w1.w, t_); \
                    sd = t_; }
                DOT8(q00,q01,s0); DOT8(q10,q11,s1);
                DOT8(q20,q21,s2); DOT8(q30,q31,s3);

#pragma unroll
                for (int off = 32; off > 0; off >>= 1) {
                    s0 += __shfl_down(s0, off, 64);
                    s1 += __shfl_down(s1, off, 64);
                    s2 += __shfl_down(s2, off, 64);
                    s3 += __shfl_down(s3, off, 64);
                }

                if (lane == 0) {
                    const int nv = nch - b;            // >= 1
                    const int libase = es - e0 + base + b;
                    { float sc = s0 + bias2; int li = libase;
                      if (li < SC_CAP) sc_lds[li] = sc; else tmp[e0 + li].x = sc; }
                    if (nv > 1) { float sc = s1 + bias2; int li = libase + 1;
                      if (li < SC_CAP) sc_lds[li] = sc; else tmp[e0 + li].x = sc; }
                    if (nv > 2) { float sc = s2 + bias2; int li = libase + 2;
                      if (li < SC_CAP) sc_lds[li] = sc; else tmp[e0 + li].x = sc; }
                    if (nv > 3) { float sc = s3 + bias2; int li = libase + 3;
                      if (li < SC_CAP) sc_lds[li] = sc; else tmp[e0 + li].x = sc; }
                }

                if (more) {
                    q00=n00; q01=n01; q10=n10; q11=n11;
                    q20=n20; q21=n21; q30=n30; q31=n31;
                }
            }
#undef QL
#undef DOT8
        }

        // ---- per-row softmax + logits, wave-local (no barrier needed:
        //      this wave wrote every sc_lds/tmp entry of this row) ----
        float m = -INFINITY;
        for (int j = lane; j < d; j += 64) {
            const int li = es - e0 + j;
            float s = (li < SC_CAP) ? sc_lds[li] : tmp[es + j].x;
            m = fmaxf(m, s);
        }
#pragma unroll
        for (int off = 32; off > 0; off >>= 1)
            m = fmaxf(m, __shfl_down(m, off, 64));
        m = __shfl(m, 0, 64);

        float ssum = 0.0f;
        for (int j = lane; j < d; j += 64) {
            const int li = es - e0 + j;
            float s = (li < SC_CAP) ? sc_lds[li] : tmp[es + j].x;
            ssum += expf(s - m);
        }
#pragma unroll
        for (int off = 32; off > 0; off >>= 1)
            ssum += __shfl_down(ssum, off, 64);
        ssum = __shfl(ssum, 0, 64);

        for (int j = lane; j < d; j += 64) {
            const int li = es - e0 + j;
            float s = (li < SC_CAP) ? sc_lds[li] : tmp[es + j].x;
            float p = expf(s - m) / ssum;
            float logits = logf(p) - log1pf(-p);   // +inf when p==1 (d==1)
            tmp[es + j] = make_float2(s, logits);  // coalesced, sorted order
        }
    }
}

// ---------------------------------------------------------------------------
// unperm: original-edge-order tail. Sequential u/edge_mask/inv reads, one 8B
// gather from the L2-resident tmp (2.56 MB), fully coalesced writes of all 5
// outputs -> no write amplification anywhere.
// ---------------------------------------------------------------------------
__global__ __launch_bounds__(256) void unperm(
    const float2* __restrict__ tmp, const int* __restrict__ inv,
    const float* __restrict__ u, const int* __restrict__ edge_mask,
    const int* __restrict__ hierarchy,
    float* __restrict__ scores, float* __restrict__ out_y,
    float* __restrict__ out_mask, float* __restrict__ out_causal,
    float* __restrict__ out_spu)
{
    const int e = blockIdx.x * 256 + threadIdx.x;
    if (e >= N_EDGES) return;
    const float2 t = tmp[inv[e]];
    const float s = t.x;
    const float uu = u[e];
    const float L = logf(uu) - log1pf(-uu);
    const float y = 1.0f / (1.0f + expf(-(t.y + L)));
    const bool hard = y > 0.5f;                    // ST forward value == y_hard
    const int mm = hard ? (hierarchy[0] + 1) : edge_mask[e];
    scores[e]     = s;
    out_y[e]      = hard ? 1.0f : 0.0f;
    out_mask[e]   = (float)mm;
    out_causal[e] = (mm > 0)   ?  s : 0.0f;
    out_spu[e]    = (mm == -1) ? -s : 0.0f;
}

// ---------------------------------------------------------------------------
extern "C" void kernel_launch(void* const* d_in, const int* in_sizes, int n_in,
                              void* d_out, int out_size, void* d_ws, size_t ws_size,
                              hipStream_t stream) {
    const float* h_ptr = (const float*)d_in[0];
    const float* W1    = (const float*)d_in[1];
    const float* b1    = (const float*)d_in[2];
    const float* W2    = (const float*)d_in[3];
    const float* b2    = (const float*)d_in[4];
    const float* u     = (const float*)d_in[5];
    const int*   row   = (const int*)d_in[6];
    const int*   col   = (const int*)d_in[7];
    const int*   emask = (const int*)d_in[8];
    const int*   hier  = (const int*)d_in[9];

    float* out        = (float*)d_out;
    float* scores     = out;                        // [E]
    float* out_y      = out + (size_t)N_EDGES;      // [E]
    float* out_mask   = out + 2 * (size_t)N_EDGES;  // [E]
    float* out_causal = out + 3 * (size_t)N_EDGES;  // [E]
    float* out_spu    = out + 4 * (size_t)N_EDGES;  // [E]

    // workspace (4B units): P, Q (16B align), tmp float2 (8B), cols16 (2B),
    // inv, then the small int arrays
    float*          P      = (float*)d_ws;
    float*          Qm     = P + (size_t)N_NODES * HID;
    float2*         tmp    = (float2*)(Qm + (size_t)N_NODES * HID);   // [E]
    unsigned short* cols16 = (unsigned short*)(tmp + N_EDGES);        // [E] u16
    int*            inv    = (int*)(cols16 + N_EDGES);                // [E]
    int*            deg    = inv + N_EDGES;
    int*            cursor = deg + N_NODES;
    int*            offs   = cursor + N_NODES;      // [N_NODES+1]
    int*            part   = offs + N_NODES + 1;
    int*            totals = part + N_NODES;        // [NCHUNK]

    hipLaunchKernelGGL(init_deg, dim3((N_NODES + 255) / 256), dim3(256), 0, stream,
                       deg, offs);

    hipLaunchKernelGGL(gemm_hist, dim3(GEMM_BLOCKS + HIST_BLOCKS), dim3(256), 0, stream,
                       h_ptr, W1, b1, P, Qm, row, deg);

    hipLaunchKernelGGL(scan_part, dim3(NCHUNK), dim3(1024), 0, stream, deg, part, totals);
    hipLaunchKernelGGL(scan_apply, dim3(NCHUNK), dim3(1024), 0, stream,
                       part, totals, cursor, offs);
    hipLaunchKernelGGL(scatter_edges, dim3((N_EDGES + 255) / 256), dim3(256), 0, stream,
                       row, col, cursor, cols16, inv);

    hipLaunchKernelGGL(fused_edge, dim3((N_NODES + ROWS_PER_BLOCK - 1) / ROWS_PER_BLOCK),
                       dim3(256), 0, stream,
                       P, Qm, W2, b2, cols16, offs, tmp);

    hipLaunchKernelGGL(unperm, dim3((N_EDGES + 255) / 256), dim3(256), 0, stream,
                       tmp, inv, u, emask, hier,
                       scores, out_y, out_mask, out_causal, out_spu);
}

// Round 2
// 275.574 us; speedup vs baseline: 1.0428x; 1.0161x over previous
//
#include <hip/hip_runtime.h>
#include <math.h>

#define N_NODES 20000
#define N_EDGES 320000
#define EMB 128
#define HID 512          // 4*EMB
#define NCHUNK ((N_NODES + 1023) / 1024)   // 20

// fused_edge geometry: 128-thr blocks (2 waves), each wave owns 4 consecutive rows
#define RPW 4
#define WPB 2
#define RPB (RPW * WPB)                    // 8
#define FE_BLOCKS ((N_NODES + RPB - 1) / RPB)  // 2500

typedef float v2f __attribute__((ext_vector_type(2)));

#if defined(__has_builtin)
#if __has_builtin(__builtin_elementwise_fma)
#define V2FMA(a, b, c) __builtin_elementwise_fma((a), (b), (c))
#else
#define V2FMA(a, b, c) ((a) * (b) + (c))
#endif
#else
#define V2FMA(a, b, c) ((a) * (b) + (c))
#endif

// ---------------------------------------------------------------------------
__global__ void init_deg(int* __restrict__ deg, int* __restrict__ offs) {
    int i = blockIdx.x * 256 + threadIdx.x;
    if (i < N_NODES) deg[i] = 0;
    if (i == 0) offs[N_NODES] = N_EDGES;
}

// ---------------------------------------------------------------------------
// K2: heterogeneous blocks — [0,GEMM_BLOCKS) = GEMM, rest = row histogram.
// GEMM: P[n][0:512] = h@W1[0:128,:] + b1 ; Q[n][0:512] = h@W1[128:256,:]
// 128x128 tile, BK=8, 256 thr, 8x8 micro (pk-fma), LDS double-buffer.
// ---------------------------------------------------------------------------
#define TM 128
#define TN 128
#define BK 8
#define NTILES (EMB / BK)                   // 16
#define GEMM_MT ((N_NODES + TM - 1) / TM)   // 157
#define GEMM_BLOCKS (8 * GEMM_MT)           // 1256
#define HIST_BLOCKS ((N_EDGES + 255) / 256) // 1250

__global__ __launch_bounds__(256) void gemm_hist(
    const float* __restrict__ h, const float* __restrict__ W1,
    const float* __restrict__ b1, float* __restrict__ P, float* __restrict__ Q,
    const int* __restrict__ row, int* __restrict__ deg)
{
    const int bid = blockIdx.x;
    const int tid = threadIdx.x;

    if (bid >= GEMM_BLOCKS) {
        // ---- histogram path ----
        const int e = (bid - GEMM_BLOCKS) * 256 + tid;
        if (e < N_EDGES) atomicAdd(&deg[row[e]], 1);
        return;
    }

    // ---- gemm path ----
    __shared__ float As[2][BK][TM + 4];
    __shared__ float Bs[2][BK][TN];

    const int nt = bid & 7;        // 0..7 (1256 = 8*157 exactly)
    const int mt = bid >> 3;       // 0..156
    const int m_base = mt * TM;

    const int a_m = tid >> 1;
    const int a_k = (tid & 1) << 2;
    const int  row_a = m_base + a_m;
    const bool a_ok  = row_a < N_NODES;
    const float* __restrict__ hrow = h + (size_t)row_a * EMB + a_k;

    const int b_k = tid >> 5;
    const int b_n = (tid & 31) << 2;
    const int w_row_off = (nt < 4) ? 0 : 128;
    const int w_col     = (nt & 3) * TN + b_n;
    const float* __restrict__ wrow = W1 + (size_t)(w_row_off + b_k) * HID + w_col;

    const int ty = tid >> 4, tx = tid & 15;
    const int cm = ty << 2, cn = tx << 2;

    v2f acc[8][4] = {};

    float4 pa, pb;
    pa = make_float4(0.f, 0.f, 0.f, 0.f);
    if (a_ok) pa = *(const float4*)(hrow);
    pb = *(const float4*)(wrow);
    As[0][a_k + 0][a_m] = pa.x;
    As[0][a_k + 1][a_m] = pa.y;
    As[0][a_k + 2][a_m] = pa.z;
    As[0][a_k + 3][a_m] = pa.w;
    *(float4*)&Bs[0][b_k][b_n] = pb;
    __syncthreads();

    for (int t = 0; t < NTILES; ++t) {
        const int cur = t & 1;
        if (t + 1 < NTILES) {
            const int k0 = (t + 1) * BK;
            pa = make_float4(0.f, 0.f, 0.f, 0.f);
            if (a_ok) pa = *(const float4*)(hrow + k0);
            pb = *(const float4*)(wrow + (size_t)k0 * HID);
        }

#pragma unroll
        for (int kk = 0; kk < BK; ++kk) {
            float a[8];
            *(float4*)&a[0] = *(const float4*)&As[cur][kk][cm];
            *(float4*)&a[4] = *(const float4*)&As[cur][kk][cm + 64];
            float4 b0 = *(const float4*)&Bs[cur][kk][cn];
            float4 b1v = *(const float4*)&Bs[cur][kk][cn + 64];
            v2f bp[4] = {(v2f){b0.x, b0.y}, (v2f){b0.z, b0.w},
                         (v2f){b1v.x, b1v.y}, (v2f){b1v.z, b1v.w}};
#pragma unroll
            for (int i = 0; i < 8; ++i) {
                v2f ai = (v2f){a[i], a[i]};
#pragma unroll
                for (int j = 0; j < 4; ++j)
                    acc[i][j] = V2FMA(ai, bp[j], acc[i][j]);
            }
        }

        if (t + 1 < NTILES) {
            const int nxt = 1 - cur;
            As[nxt][a_k + 0][a_m] = pa.x;
            As[nxt][a_k + 1][a_m] = pa.y;
            As[nxt][a_k + 2][a_m] = pa.z;
            As[nxt][a_k + 3][a_m] = pa.w;
            *(float4*)&Bs[nxt][b_k][b_n] = pb;
            __syncthreads();
        }
    }

    const bool  isP = (nt < 4);
    const int   col_base = (nt & 3) * TN;
    float* __restrict__ dstbase = isP ? P : Q;

    v2f bias[4] = {{0.f,0.f},{0.f,0.f},{0.f,0.f},{0.f,0.f}};
    if (isP) {  // bias fold: P half only
        float4 bv0 = *(const float4*)(b1 + col_base + cn);
        float4 bv1 = *(const float4*)(b1 + col_base + cn + 64);
        bias[0] = (v2f){bv0.x, bv0.y};
        bias[1] = (v2f){bv0.z, bv0.w};
        bias[2] = (v2f){bv1.x, bv1.y};
        bias[3] = (v2f){bv1.z, bv1.w};
    }

#pragma unroll
    for (int i = 0; i < 8; ++i) {
        const int r = m_base + cm + (i < 4 ? i : 64 + i - 4);
        if (r < N_NODES) {
            float* dst = dstbase + (size_t)r * HID + col_base;
            v2f c0 = acc[i][0] + bias[0], c1 = acc[i][1] + bias[1];
            v2f c2 = acc[i][2] + bias[2], c3 = acc[i][3] + bias[3];
            *(float4*)(dst + cn)      = make_float4(c0.x, c0.y, c1.x, c1.y);
            *(float4*)(dst + cn + 64) = make_float4(c2.x, c2.y, c3.x, c3.y);
        }
    }
}

// ---------------------------------------------------------------------------
__device__ __forceinline__ int wave_incl_scan(int v, int lane) {
#pragma unroll
    for (int off = 1; off < 64; off <<= 1) {
        int t = __shfl_up(v, off, 64);
        if (lane >= off) v += t;
    }
    return v;
}

__global__ __launch_bounds__(1024) void scan_part(const int* __restrict__ deg,
                                                  int* __restrict__ part,
                                                  int* __restrict__ totals) {
    __shared__ int wsum[16];
    const int tid = threadIdx.x, lane = tid & 63, w = tid >> 6;
    const int i = blockIdx.x * 1024 + tid;
    int v = (i < N_NODES) ? deg[i] : 0;
    int incl = wave_incl_scan(v, lane);
    if (lane == 63) wsum[w] = incl;
    __syncthreads();
    if (w == 0) {
        int x = (lane < 16) ? wsum[lane] : 0;
        int xs = wave_incl_scan(x, lane);
        if (lane < 16) wsum[lane] = xs - x;
        if (lane == 15) totals[blockIdx.x] = xs;
    }
    __syncthreads();
    if (i < N_NODES) part[i] = wsum[w] + incl - v;
}

__global__ __launch_bounds__(1024) void scan_apply(const int* __restrict__ part,
                                                   const int* __restrict__ totals,
                                                   int* __restrict__ cursor,
                                                   int* __restrict__ offs) {
    __shared__ int carry_s;
    const int tid = threadIdx.x;
    if (tid < 64) {
        int v = (tid < NCHUNK) ? totals[tid] : 0;
        int incl = wave_incl_scan(v, tid);
        if (tid == (int)blockIdx.x) carry_s = incl - v;   // exclusive carry
    }
    __syncthreads();
    const int i = blockIdx.x * 1024 + tid;
    if (i < N_NODES) {
        int o = part[i] + carry_s;
        cursor[i] = o;
        offs[i] = o;
    }
}

// ---------------------------------------------------------------------------
// scatter: cols16[pos] = col (u16) in CSR order; inv[e] = pos so unperm runs
// in ORIGINAL edge order with coalesced output writes.
// ---------------------------------------------------------------------------
__global__ void scatter_edges(const int* __restrict__ row, const int* __restrict__ col,
                              int* __restrict__ cursor,
                              unsigned short* __restrict__ cols16,
                              int* __restrict__ inv) {
    int e = blockIdx.x * 256 + threadIdx.x;
    if (e >= N_EDGES) return;
    int r = row[e];
    int pos = atomicAdd(&cursor[r], 1);
    cols16[pos] = (unsigned short)col[e];
    inv[e] = pos;
}

// ---------------------------------------------------------------------------
// Fused edge phase, round-2 restructure (concurrency-first):
//  * lane-owns-edge: lane L computes/keeps the score of edge es+base+L.
//    Batch-2 / depth-1 register pipeline (2+2 float4 of Q = 32 VGPR, was 64)
//    -> target VGPR ~48 to regain the occupancy tier lost in round-1.
//  * in-register softmax for d<=64 rows (virtually all; Poisson λ=16):
//    butterfly shfl_xor reductions, straight-line lane math — NO LDS, no
//    lane0 serialization, no strided re-read passes. d>64 rows use the
//    old tmp.x spill + 3-pass path (rare -> cost irrelevant).
//  * 128-thr blocks (2 waves), each wave owns 4 consecutive rows; zero LDS,
//    zero __syncthreads, fine scheduling granularity.
// DOT8 fmaf chain + bias2 placement bit-identical to previous rounds; only
// the reduction tree shape changed (xor-butterfly), a reassociation-level
// difference of the same kind that already passes.
// ---------------------------------------------------------------------------
__device__ __forceinline__ float dot8_relu(const float4 qa, const float4 qb,
                                           const float4 p0, const float4 p1,
                                           const float4 w0, const float4 w1) {
    float t = 0.0f;
    t = fmaf(fmaxf(p0.x + qa.x, 0.0f), w0.x, t);
    t = fmaf(fmaxf(p0.y + qa.y, 0.0f), w0.y, t);
    t = fmaf(fmaxf(p0.z + qa.z, 0.0f), w0.z, t);
    t = fmaf(fmaxf(p0.w + qa.w, 0.0f), w0.w, t);
    t = fmaf(fmaxf(p1.x + qb.x, 0.0f), w1.x, t);
    t = fmaf(fmaxf(p1.y + qb.y, 0.0f), w1.y, t);
    t = fmaf(fmaxf(p1.z + qb.z, 0.0f), w1.z, t);
    t = fmaf(fmaxf(p1.w + qb.w, 0.0f), w1.w, t);
    return t;
}

// Computes per-lane score for one chunk of <=64 edges [es+base, es+base+nch).
// Returns the score (+bias2) in the owning lane's register; -INF elsewhere.
__device__ __forceinline__ float chunk_scores(
    const float* __restrict__ Q, const unsigned short* __restrict__ cols16,
    int es_base, int nch, int lane, int j0,
    const float4 p0, const float4 p1, const float4 w0, const float4 w1,
    float bias2)
{
    int mycol = 0;
    if (lane < nch) mycol = (int)cols16[es_base + lane];
    float mysc = -INFINITY;

#define QL2(k, bb, d0, d1) { \
        int c_ = __shfl(mycol, (bb) + (k), 64); \
        const float* __restrict__ q_ = Q + (size_t)c_ * HID; \
        d0 = *(const float4*)(q_ + j0); \
        d1 = *(const float4*)(q_ + 256 + j0); }

    float4 a00, a01, a10, a11;
    QL2(0, 0, a00, a01); QL2(1, 0, a10, a11);

    for (int b = 0; b < nch; b += 2) {
        float4 n00, n01, n10, n11;
        const bool more = (b + 2) < nch;
        if (more) { QL2(0, b + 2, n00, n01); QL2(1, b + 2, n10, n11); }

        float s0 = dot8_relu(a00, a01, p0, p1, w0, w1);
        float s1 = dot8_relu(a10, a11, p0, p1, w0, w1);

#pragma unroll
        for (int off = 32; off > 0; off >>= 1) {
            s0 += __shfl_xor(s0, off, 64);
            s1 += __shfl_xor(s1, off, 64);
        }

        const int k = lane - b;
        if ((unsigned)k < 2u && lane < nch) mysc = (k ? s1 : s0) + bias2;

        if (more) { a00 = n00; a01 = n01; a10 = n10; a11 = n11; }
    }
#undef QL2
    return mysc;
}

__global__ __launch_bounds__(128) void fused_edge(
    const float* __restrict__ P, const float* __restrict__ Q,
    const float* __restrict__ W2, const float* __restrict__ b2,
    const unsigned short* __restrict__ cols16, const int* __restrict__ offs,
    float2* __restrict__ tmp)
{
    const int tid = threadIdx.x, lane = tid & 63, w = tid >> 6;
    const int r0 = blockIdx.x * RPB + w * RPW;
    const int r1 = (r0 + RPW < N_NODES) ? r0 + RPW : N_NODES;
    const int j0 = lane << 2;

    const float4 w0 = *(const float4*)(W2 + j0);
    const float4 w1 = *(const float4*)(W2 + 256 + j0);
    const float bias2 = b2[0];

    for (int r = r0; r < r1; ++r) {
        const int es = offs[r], ee = offs[r + 1];
        const int d = ee - es;
        if (d == 0) continue;

        const float* __restrict__ prow = P + (size_t)r * HID;
        const float4 p0 = *(const float4*)(prow + j0);
        const float4 p1 = *(const float4*)(prow + 256 + j0);

        if (d <= 64) {
            // ---- common path: whole row in one chunk, softmax in registers
            float mysc = chunk_scores(Q, cols16, es, d, lane, j0,
                                      p0, p1, w0, w1, bias2);

            float m = mysc;
#pragma unroll
            for (int off = 32; off > 0; off >>= 1)
                m = fmaxf(m, __shfl_xor(m, off, 64));

            float ev = (lane < d) ? expf(mysc - m) : 0.0f;
            float ssum = ev;
#pragma unroll
            for (int off = 32; off > 0; off >>= 1)
                ssum += __shfl_xor(ssum, off, 64);

            if (lane < d) {
                float p = ev / ssum;
                float logits = logf(p) - log1pf(-p);   // +inf when p==1 (d==1)
                tmp[es + lane] = make_float2(mysc, logits);
            }
        } else {
            // ---- rare spill path: chunked scores -> tmp.x, then 3 passes
            for (int base = 0; base < d; base += 64) {
                const int nch = (d - base < 64) ? d - base : 64;
                float mysc = chunk_scores(Q, cols16, es + base, nch, lane, j0,
                                          p0, p1, w0, w1, bias2);
                if (lane < nch) tmp[es + base + lane].x = mysc;
            }

            float m = -INFINITY;
            for (int j = lane; j < d; j += 64)
                m = fmaxf(m, tmp[es + j].x);
#pragma unroll
            for (int off = 32; off > 0; off >>= 1)
                m = fmaxf(m, __shfl_xor(m, off, 64));

            float ssum = 0.0f;
            for (int j = lane; j < d; j += 64)
                ssum += expf(tmp[es + j].x - m);
#pragma unroll
            for (int off = 32; off > 0; off >>= 1)
                ssum += __shfl_xor(ssum, off, 64);

            for (int j = lane; j < d; j += 64) {
                float s = tmp[es + j].x;
                float p = expf(s - m) / ssum;
                float logits = logf(p) - log1pf(-p);
                tmp[es + j] = make_float2(s, logits);
            }
        }
    }
}

// ---------------------------------------------------------------------------
// unperm: original-edge-order tail. Sequential u/edge_mask/inv reads, one 8B
// gather from the L2-resident tmp (2.56 MB), fully coalesced writes of all 5
// outputs.
// ---------------------------------------------------------------------------
__global__ __launch_bounds__(256) void unperm(
    const float2* __restrict__ tmp, const int* __restrict__ inv,
    const float* __restrict__ u, const int* __restrict__ edge_mask,
    const int* __restrict__ hierarchy,
    float* __restrict__ scores, float* __restrict__ out_y,
    float* __restrict__ out_mask, float* __restrict__ out_causal,
    float* __restrict__ out_spu)
{
    const int e = blockIdx.x * 256 + threadIdx.x;
    if (e >= N_EDGES) return;
    const float2 t = tmp[inv[e]];
    const float s = t.x;
    const float uu = u[e];
    const float L = logf(uu) - log1pf(-uu);
    const float y = 1.0f / (1.0f + expf(-(t.y + L)));
    const bool hard = y > 0.5f;                    // ST forward value == y_hard
    const int mm = hard ? (hierarchy[0] + 1) : edge_mask[e];
    scores[e]     = s;
    out_y[e]      = hard ? 1.0f : 0.0f;
    out_mask[e]   = (float)mm;
    out_causal[e] = (mm > 0)   ?  s : 0.0f;
    out_spu[e]    = (mm == -1) ? -s : 0.0f;
}

// ---------------------------------------------------------------------------
extern "C" void kernel_launch(void* const* d_in, const int* in_sizes, int n_in,
                              void* d_out, int out_size, void* d_ws, size_t ws_size,
                              hipStream_t stream) {
    const float* h_ptr = (const float*)d_in[0];
    const float* W1    = (const float*)d_in[1];
    const float* b1    = (const float*)d_in[2];
    const float* W2    = (const float*)d_in[3];
    const float* b2    = (const float*)d_in[4];
    const float* u     = (const float*)d_in[5];
    const int*   row   = (const int*)d_in[6];
    const int*   col   = (const int*)d_in[7];
    const int*   emask = (const int*)d_in[8];
    const int*   hier  = (const int*)d_in[9];

    float* out        = (float*)d_out;
    float* scores     = out;                        // [E]
    float* out_y      = out + (size_t)N_EDGES;      // [E]
    float* out_mask   = out + 2 * (size_t)N_EDGES;  // [E]
    float* out_causal = out + 3 * (size_t)N_EDGES;  // [E]
    float* out_spu    = out + 4 * (size_t)N_EDGES;  // [E]

    // workspace (4B units): P, Q (16B align), tmp float2 (8B), cols16 (2B),
    // inv, then the small int arrays
    float*          P      = (float*)d_ws;
    float*          Qm     = P + (size_t)N_NODES * HID;
    float2*         tmp    = (float2*)(Qm + (size_t)N_NODES * HID);   // [E]
    unsigned short* cols16 = (unsigned short*)(tmp + N_EDGES);        // [E] u16
    int*            inv    = (int*)(cols16 + N_EDGES);                // [E]
    int*            deg    = inv + N_EDGES;
    int*            cursor = deg + N_NODES;
    int*            offs   = cursor + N_NODES;      // [N_NODES+1]
    int*            part   = offs + N_NODES + 1;
    int*            totals = part + N_NODES;        // [NCHUNK]

    hipLaunchKernelGGL(init_deg, dim3((N_NODES + 255) / 256), dim3(256), 0, stream,
                       deg, offs);

    hipLaunchKernelGGL(gemm_hist, dim3(GEMM_BLOCKS + HIST_BLOCKS), dim3(256), 0, stream,
                       h_ptr, W1, b1, P, Qm, row, deg);

    hipLaunchKernelGGL(scan_part, dim3(NCHUNK), dim3(1024), 0, stream, deg, part, totals);
    hipLaunchKernelGGL(scan_apply, dim3(NCHUNK), dim3(1024), 0, stream,
                       part, totals, cursor, offs);
    hipLaunchKernelGGL(scatter_edges, dim3((N_EDGES + 255) / 256), dim3(256), 0, stream,
                       row, col, cursor, cols16, inv);

    hipLaunchKernelGGL(fused_edge, dim3(FE_BLOCKS), dim3(128), 0, stream,
                       P, Qm, W2, b2, cols16, offs, tmp);

    hipLaunchKernelGGL(unperm, dim3((N_EDGES + 255) / 256), dim3(256), 0, stream,
                       tmp, inv, u, emask, hier,
                       scores, out_y, out_mask, out_causal, out_spu);
}